// Round 2
// 178.062 us; speedup vs baseline: 1.0235x; 1.0235x over previous
//
#include <hip/hip_runtime.h>

// Nearest-neighbor gather resample.
// idx:    [B, 2, N] float32 (row, col) coords
// source: [B, 640, 640, 3] float32
// out:    [B, N, 3] float32; zero where rounded coord out of bounds.
//
// Semantics: coord = (int)truncf(v + 0.5f)  -- trunc toward zero, matching
// jnp.trunc(idx+0.5).astype(int32). Validity tested on UNCLAMPED coord.
//
// R2 changes vs baseline (182.5us / 71.4us-per-dispatch):
//  - XCD batch-affinity swizzle: blocks dispatch round-robin over 8 XCDs;
//    remap so each XCD owns a contiguous 1/8 of the grid (= 2 batches,
//    9.8 MB source slice) -> better L2 gather hit rate, no cross-XCD
//    duplication of source lines.
//  - Nontemporal idx loads + out stores: both are streamed exactly once;
//    keep them from evicting the randomly-gathered source out of L2/L3.
//  - (fix vs R1: nontemporal builtins need clang ext_vector_type, not the
//    HIP_vector_type class float4.)

#define HS 640
#define WS 640
#define NC 3
#define NXCD 8

typedef float v4f __attribute__((ext_vector_type(4)));

__global__ __launch_bounds__(256) void resample_nn_kernel(
    const float* __restrict__ idx,   // [B, 2, N]
    const float* __restrict__ src,   // [B, HS, WS, NC]
    float* __restrict__ out,         // [B, N, NC]
    int N)                           // pixels per batch (quad-divisible)
{
    const int quads_per_b = N >> 2;

    // --- XCD batch-affinity swizzle (bijective when gridDim.x % 8 == 0) ---
    int bid = blockIdx.x;
    int nb  = gridDim.x;
    if ((nb & (NXCD - 1)) == 0) {
        int per = nb >> 3;                       // blocks per XCD
        bid = (bid & (NXCD - 1)) * per + (bid >> 3);
    }

    long long tid = (long long)bid * blockDim.x + threadIdx.x;
    int b = (int)(tid / quads_per_b);
    int q = (int)(tid % quads_per_b);
    int n0 = q << 2;

    const float* idx_b = idx + (size_t)b * 2 * N;
    // idx is read exactly once -> nontemporal so it doesn't pollute the
    // caches that the source gather depends on.
    v4f r4 = __builtin_nontemporal_load((const v4f*)(idx_b + n0));
    v4f c4 = __builtin_nontemporal_load((const v4f*)(idx_b + N + n0));

    const float* src_b = src + (size_t)b * (HS * WS * NC);

    float rr[4] = {r4.x, r4.y, r4.z, r4.w};
    float cc[4] = {c4.x, c4.y, c4.z, c4.w};

    float v[12];
#pragma unroll
    for (int i = 0; i < 4; ++i) {
        // trunc-toward-zero conversion == jnp.trunc().astype(int32)
        int ir = (int)(rr[i] + 0.5f);
        int ic = (int)(cc[i] + 0.5f);
        bool valid = (ir >= 0) & (ic >= 0) & (ir < HS) & (ic < WS);
        int irc = min(max(ir, 0), HS - 1);
        int icc = min(max(ic, 0), WS - 1);
        const float* p = src_b + ((size_t)irc * WS + icc) * NC;
        // clamped address is always in-bounds -> unconditional loads + select
        float x = p[0], y = p[1], z = p[2];
        v[3 * i + 0] = valid ? x : 0.0f;
        v[3 * i + 1] = valid ? y : 0.0f;
        v[3 * i + 2] = valid ? z : 0.0f;
    }

    // out is written exactly once -> nontemporal stores (streaming).
    v4f* o = (v4f*)(out + ((size_t)b * N + n0) * NC);
    v4f o0 = {v[0], v[1], v[2], v[3]};
    v4f o1 = {v[4], v[5], v[6], v[7]};
    v4f o2 = {v[8], v[9], v[10], v[11]};
    __builtin_nontemporal_store(o0, o + 0);
    __builtin_nontemporal_store(o1, o + 1);
    __builtin_nontemporal_store(o2, o + 2);
}

extern "C" void kernel_launch(void* const* d_in, const int* in_sizes, int n_in,
                              void* d_out, int out_size, void* d_ws, size_t ws_size,
                              hipStream_t stream) {
    const float* idx = (const float*)d_in[0];
    const float* src = (const float*)d_in[1];
    float* out = (float*)d_out;

    // source is [B, 640, 640, 3]; idx is [B, 2, N]
    int B = in_sizes[1] / (HS * WS * NC);        // 16
    int N = in_sizes[0] / (2 * B);               // 262144

    long long total_quads = (long long)B * (N >> 2);   // 1,048,576 threads
    int block = 256;
    int grid = (int)((total_quads + block - 1) / block);

    resample_nn_kernel<<<grid, block, 0, stream>>>(idx, src, out, N);
}